// Round 1
// baseline (1437.909 us; speedup 1.0000x reference)
//
#include <hip/hip_runtime.h>
#include <hip/hip_bf16.h>

// Problem: N=50000 nodes, F=H=512, E=160000 edges.
// out = BN_train( (x + scatter_sum(x[src]->dst)) @ W^T + b ) ; bias b cancels in BN.
// ws layout: h[N*512 f32] | Wb[512*512 bf16] | s1[512] | s2[512] | scale[512] | shift[512] | flag
// ws required ~103 MB.

typedef __attribute__((ext_vector_type(8))) short short8;
typedef __attribute__((ext_vector_type(4))) float floatx4;

static __device__ __forceinline__ unsigned short f2bf(float f) {
    unsigned int u = __float_as_uint(f);
    u += 0x7FFFu + ((u >> 16) & 1u);   // round-to-nearest-even
    return (unsigned short)(u >> 16);
}

// ---- detect whether edge_index is int64 (odd int32 words all zero) or int32 ----
__global__ void detect_dtype(const int* __restrict__ ei, int* __restrict__ flag) {
    __shared__ int any_nz;
    if (threadIdx.x == 0) any_nz = 0;
    __syncthreads();
    if (ei[2 * threadIdx.x + 1] != 0) atomicOr(&any_nz, 1);
    __syncthreads();
    if (threadIdx.x == 0) *flag = (any_nz == 0) ? 1 : 0;  // 1 => int64 layout
}

// ---- W fp32 -> bf16, and zero the stats accumulators ----
__global__ __launch_bounds__(256) void conv_w(const float* __restrict__ W,
                                              unsigned short* __restrict__ Wb,
                                              float* __restrict__ stats /*1024 floats*/) {
    int i = blockIdx.x * 256 + threadIdx.x;   // 65536 threads x 4 elems = 512*512
    float4 v = ((const float4*)W)[i];
    ushort4 u;
    u.x = f2bf(v.x); u.y = f2bf(v.y); u.z = f2bf(v.z); u.w = f2bf(v.w);
    ((ushort4*)Wb)[i] = u;
    if (blockIdx.x == 0) {
        stats[threadIdx.x] = 0.f;
        stats[256 + threadIdx.x] = 0.f;
        stats[512 + threadIdx.x] = 0.f;
        stats[768 + threadIdx.x] = 0.f;
    }
}

// ---- h = x (vectorized copy) ----
__global__ __launch_bounds__(256) void copy_x(const float4* __restrict__ x,
                                              float4* __restrict__ h, int n4) {
    int i = blockIdx.x * 256 + threadIdx.x;
    if (i < n4) h[i] = x[i];
}

// ---- h[dst] += x[src], one wave (64 lanes) per edge, 8 floats/lane ----
__global__ __launch_bounds__(256) void scatter_add(const int* __restrict__ ei,
                                                   const float* __restrict__ x,
                                                   float* __restrict__ h,
                                                   const int* __restrict__ flag,
                                                   int E, int N) {
    int t = blockIdx.x * 256 + threadIdx.x;
    int e = t >> 6;
    if (e >= E) return;
    int lane = t & 63;
    int s, d;
    if (*flag) {
        const long long* e64 = (const long long*)ei;
        s = (int)e64[e];
        d = (int)e64[E + e];
    } else {
        s = ei[e];
        d = ei[E + e];
    }
    if ((unsigned)s >= (unsigned)N || (unsigned)d >= (unsigned)N) return;
    const float4* xs = (const float4*)(x + (size_t)s * 512);
    float* hd = h + (size_t)d * 512;
#pragma unroll
    for (int i = 0; i < 2; ++i) {
        float4 v = xs[lane + 64 * i];
        int b = (lane + 64 * i) * 4;
        unsafeAtomicAdd(hd + b + 0, v.x);
        unsafeAtomicAdd(hd + b + 1, v.y);
        unsafeAtomicAdd(hd + b + 2, v.z);
        unsafeAtomicAdd(hd + b + 3, v.w);
    }
}

// ---- z = h @ Wb^T  (A [N,512] f32 -> bf16 staged; B [512,512] bf16 row-major-K) ----
#define LDSS 88   // bf16 elems per row: 176 B, 16B-aligned, 12-bank rotation
__global__ __launch_bounds__(256) void gemm_bt(const float* __restrict__ h,
                                               const unsigned short* __restrict__ Wb,
                                               float* __restrict__ z, int N) {
    __shared__ unsigned short As[128 * LDSS];
    __shared__ unsigned short Bs[128 * LDSS];
    int tid = threadIdx.x;
    int wave = tid >> 6, lane = tid & 63;
    int quad = lane >> 4, l16 = lane & 15;
    int row0 = blockIdx.x * 128;
    int col0 = blockIdx.y * 128;
    int wr = (wave >> 1) * 64, wc = (wave & 1) * 64;

    floatx4 acc[4][4] = {};

    for (int k0 = 0; k0 < 512; k0 += 64) {
        // stage A: 128 rows x 64 k, fp32 -> bf16
        {
            int c4 = tid & 15;       // float4 index along k
            int rbase = tid >> 4;    // 0..15
#pragma unroll
            for (int p = 0; p < 8; ++p) {
                int r = p * 16 + rbase;
                int gr = row0 + r; if (gr >= N) gr = N - 1;
                float4 v = *(const float4*)(h + (size_t)gr * 512 + k0 + c4 * 4);
                ushort4 u;
                u.x = f2bf(v.x); u.y = f2bf(v.y); u.z = f2bf(v.z); u.w = f2bf(v.w);
                *(ushort4*)(As + r * LDSS + c4 * 4) = u;
            }
        }
        // stage B: 128 cols x 64 k, already bf16 (16B chunks)
        {
            int c8 = tid & 7;
            int rbase = tid >> 3;    // 0..31
#pragma unroll
            for (int p = 0; p < 4; ++p) {
                int r = p * 32 + rbase;
                float4 v = *(const float4*)(Wb + (size_t)(col0 + r) * 512 + k0 + c8 * 8);
                *(float4*)(Bs + r * LDSS + c8 * 8) = v;
            }
        }
        __syncthreads();
#pragma unroll
        for (int kk = 0; kk < 2; ++kk) {
            short8 af[4], bfr[4];
#pragma unroll
            for (int i = 0; i < 4; ++i) {
                af[i]  = *(const short8*)(As + (wr + i * 16 + l16) * LDSS + kk * 32 + quad * 8);
                bfr[i] = *(const short8*)(Bs + (wc + i * 16 + l16) * LDSS + kk * 32 + quad * 8);
            }
#pragma unroll
            for (int i = 0; i < 4; ++i)
#pragma unroll
                for (int j = 0; j < 4; ++j)
                    acc[i][j] = __builtin_amdgcn_mfma_f32_16x16x32_bf16(af[i], bfr[j], acc[i][j], 0, 0, 0);
        }
        __syncthreads();
    }
    // epilogue: C/D layout col=lane&15, row=quad*4+reg
#pragma unroll
    for (int i = 0; i < 4; ++i) {
        int rl = wr + i * 16 + quad * 4;
#pragma unroll
        for (int j = 0; j < 4; ++j) {
            int col = col0 + wc + j * 16 + l16;
#pragma unroll
            for (int r = 0; r < 4; ++r) {
                int grow = row0 + rl + r;
                if (grow < N) z[(size_t)grow * 512 + col] = acc[i][j][r];
            }
        }
    }
}

// ---- per-column sum & sumsq over N rows ----
__global__ __launch_bounds__(512) void col_stats(const float* __restrict__ z,
                                                 float* __restrict__ s1,
                                                 float* __restrict__ s2, int N) {
    int col = threadIdx.x;
    float a = 0.f, b = 0.f;
    for (int r = blockIdx.x; r < N; r += gridDim.x) {
        float v = z[(size_t)r * 512 + col];
        a += v;
        b += v * v;
    }
    unsafeAtomicAdd(&s1[col], a);
    unsafeAtomicAdd(&s2[col], b);
}

__global__ void finalize(const float* __restrict__ s1, const float* __restrict__ s2,
                         const float* __restrict__ gamma, const float* __restrict__ beta,
                         float* __restrict__ scale, float* __restrict__ shift, int N) {
    int c = threadIdx.x;  // 512
    float inv = 1.f / (float)N;
    float mean = s1[c] * inv;
    float var = s2[c] * inv - mean * mean;
    if (var < 0.f) var = 0.f;
    float sc = gamma[c] * rsqrtf(var + 1e-5f);
    scale[c] = sc;
    shift[c] = beta[c] - mean * sc;
}

// ---- out = z * scale[col] + shift[col], in place on d_out ----
__global__ __launch_bounds__(256) void bn_apply(float4* __restrict__ z,
                                                const float4* __restrict__ scale,
                                                const float4* __restrict__ shift, int n4) {
    int i = blockIdx.x * 256 + threadIdx.x;
    if (i >= n4) return;
    int c4 = i & 127;   // 512/4 float4 per row
    float4 v = z[i], sc = scale[c4], sh = shift[c4];
    v.x = v.x * sc.x + sh.x;
    v.y = v.y * sc.y + sh.y;
    v.z = v.z * sc.z + sh.z;
    v.w = v.w * sc.w + sh.w;
    z[i] = v;
}

extern "C" void kernel_launch(void* const* d_in, const int* in_sizes, int n_in,
                              void* d_out, int out_size, void* d_ws, size_t ws_size,
                              hipStream_t stream) {
    const float* x     = (const float*)d_in[0];
    const int*   ei    = (const int*)d_in[1];
    const float* W     = (const float*)d_in[3];
    const float* gamma = (const float*)d_in[5];
    const float* beta  = (const float*)d_in[6];
    float* out = (float*)d_out;

    int N = in_sizes[0] / 512;   // 50000
    int E = in_sizes[1] / 2;     // 160000

    char* ws = (char*)d_ws;
    float* h = (float*)ws;
    size_t off = (size_t)N * 512 * 4;
    unsigned short* Wb = (unsigned short*)(ws + off); off += 512 * 512 * 2;
    float* s1    = (float*)(ws + off); off += 2048;
    float* s2    = (float*)(ws + off); off += 2048;
    float* scale = (float*)(ws + off); off += 2048;
    float* shift = (float*)(ws + off); off += 2048;
    int*   flag  = (int*)(ws + off);   off += 256;

    int n4 = N * 128;  // float4 count of [N,512]

    hipLaunchKernelGGL(detect_dtype, dim3(1), dim3(256), 0, stream, ei, flag);
    hipLaunchKernelGGL(conv_w, dim3(256), dim3(256), 0, stream, W, Wb, s1);
    hipLaunchKernelGGL(copy_x, dim3((n4 + 255) / 256), dim3(256), 0, stream,
                       (const float4*)x, (float4*)h, n4);
    hipLaunchKernelGGL(scatter_add, dim3((E * 64 + 255) / 256), dim3(256), 0, stream,
                       ei, x, h, flag, E, N);
    hipLaunchKernelGGL(gemm_bt, dim3((N + 127) / 128, 4), dim3(256), 0, stream, h, Wb, out, N);
    hipLaunchKernelGGL(col_stats, dim3(256), dim3(512), 0, stream, out, s1, s2, N);
    hipLaunchKernelGGL(finalize, dim3(1), dim3(512), 0, stream, s1, s2, gamma, beta, scale, shift, N);
    hipLaunchKernelGGL(bn_apply, dim3((n4 + 255) / 256), dim3(256), 0, stream,
                       (float4*)out, (const float4*)scale, (const float4*)shift, n4);
}

// Round 2
// 452.331 us; speedup vs baseline: 3.1789x; 3.1789x over previous
//
#include <hip/hip_runtime.h>
#include <hip/hip_bf16.h>

// GIN encoder: out = BN_train( (x + scatter_sum(x[src]->dst)) @ W^T + b ), b cancels in BN.
// N=50000, F=H=512, E=160000.
// R2: bucket-by-dst + gather aggregation (no fp32 atomics); h stored as bf16.
// ws: hb[N*512 bf16] | Wb[512*512 bf16] | s1|s2|scale|shift[512 f32 each] | flag |
//     deg[N] | cursor[N] | offs[N+1] | srcbuf[E]   (~53 MB)

typedef __attribute__((ext_vector_type(8))) short short8;
typedef __attribute__((ext_vector_type(4))) float floatx4;

static __device__ __forceinline__ unsigned short f2bf(float f) {
    unsigned int u = __float_as_uint(f);
    u += 0x7FFFu + ((u >> 16) & 1u);   // round-to-nearest-even
    return (unsigned short)(u >> 16);
}

// ---- detect whether edge_index is int64 (odd int32 words all zero) or int32 ----
__global__ void detect_dtype(const int* __restrict__ ei, int* __restrict__ flag) {
    __shared__ int any_nz;
    if (threadIdx.x == 0) any_nz = 0;
    __syncthreads();
    if (ei[2 * threadIdx.x + 1] != 0) atomicOr(&any_nz, 1);
    __syncthreads();
    if (threadIdx.x == 0) *flag = (any_nz == 0) ? 1 : 0;  // 1 => int64 layout
}

static __device__ __forceinline__ void load_edge(const int* ei, int flag, int E, int e,
                                                 int& s, int& d) {
    if (flag) {
        const long long* e64 = (const long long*)ei;
        s = (int)e64[e];
        d = (int)e64[E + e];
    } else {
        s = ei[e];
        d = ei[E + e];
    }
}

// ---- W fp32 -> bf16, and zero the stats accumulators ----
__global__ __launch_bounds__(256) void conv_w(const float* __restrict__ W,
                                              unsigned short* __restrict__ Wb,
                                              float* __restrict__ stats /*1024 floats*/) {
    int i = blockIdx.x * 256 + threadIdx.x;   // 65536 threads x 4 elems = 512*512
    float4 v = ((const float4*)W)[i];
    ushort4 u;
    u.x = f2bf(v.x); u.y = f2bf(v.y); u.z = f2bf(v.z); u.w = f2bf(v.w);
    ((ushort4*)Wb)[i] = u;
    if (blockIdx.x == 0) {
        stats[threadIdx.x] = 0.f;
        stats[256 + threadIdx.x] = 0.f;
        stats[512 + threadIdx.x] = 0.f;
        stats[768 + threadIdx.x] = 0.f;
    }
}

// ---- zero deg + cursor (2N ints) ----
__global__ __launch_bounds__(256) void init_zero(int* __restrict__ p, int n) {
    int i = blockIdx.x * 256 + threadIdx.x;
    if (i < n) p[i] = 0;
}

// ---- per-dst degree count ----
__global__ __launch_bounds__(256) void deg_count(const int* __restrict__ ei,
                                                 const int* __restrict__ flag,
                                                 int* __restrict__ deg, int E, int N) {
    int e = blockIdx.x * 256 + threadIdx.x;
    if (e >= E) return;
    int s, d;
    load_edge(ei, *flag, E, e, s, d);
    if ((unsigned)d < (unsigned)N) atomicAdd(&deg[d], 1);
}

// ---- single-block exclusive scan of deg[N] -> offs[N+1] ----
__global__ __launch_bounds__(1024) void scan_deg(const int* __restrict__ deg,
                                                 int* __restrict__ offs, int N) {
    __shared__ int sums[1024];
    int t = threadIdx.x;
    int per = (N + 1023) / 1024;
    int beg = t * per, end = beg + per; if (end > N) end = N; if (beg > N) beg = N;
    int s = 0;
    for (int i = beg; i < end; ++i) s += deg[i];
    sums[t] = s;
    __syncthreads();
    for (int d = 1; d < 1024; d <<= 1) {
        int v = (t >= d) ? sums[t - d] : 0;
        __syncthreads();
        sums[t] += v;
        __syncthreads();
    }
    int run = (t > 0) ? sums[t - 1] : 0;
    for (int i = beg; i < end; ++i) { offs[i] = run; run += deg[i]; }
    if (t == 0) offs[N] = sums[1023];
}

// ---- scatter src indices into dst buckets ----
__global__ __launch_bounds__(256) void bucket_fill(const int* __restrict__ ei,
                                                   const int* __restrict__ flag,
                                                   const int* __restrict__ offs,
                                                   int* __restrict__ cursor,
                                                   int* __restrict__ srcbuf, int E, int N) {
    int e = blockIdx.x * 256 + threadIdx.x;
    if (e >= E) return;
    int s, d;
    load_edge(ei, *flag, E, e, s, d);
    if ((unsigned)d >= (unsigned)N || (unsigned)s >= (unsigned)N) return;
    int pos = offs[d] + atomicAdd(&cursor[d], 1);
    srcbuf[pos] = s;
}

// ---- h[n] = bf16( x[n] + sum_{s in bucket(n)} x[s] ); one wave per node ----
__global__ __launch_bounds__(256) void aggregate(const float* __restrict__ x,
                                                 const int* __restrict__ offs,
                                                 const int* __restrict__ srcbuf,
                                                 unsigned short* __restrict__ hb, int N) {
    int n = blockIdx.x * 4 + (threadIdx.x >> 6);
    if (n >= N) return;
    int lane = threadIdx.x & 63;
    const float4* xr = (const float4*)(x + (size_t)n * 512);
    float4 a0 = xr[lane];
    float4 a1 = xr[64 + lane];
    int beg = offs[n], end = offs[n + 1];
    for (int j = beg; j < end; ++j) {
        int s = srcbuf[j];
        const float4* xs = (const float4*)(x + (size_t)s * 512);
        float4 v0 = xs[lane], v1 = xs[64 + lane];
        a0.x += v0.x; a0.y += v0.y; a0.z += v0.z; a0.w += v0.w;
        a1.x += v1.x; a1.y += v1.y; a1.z += v1.z; a1.w += v1.w;
    }
    ushort4 u0, u1;
    u0.x = f2bf(a0.x); u0.y = f2bf(a0.y); u0.z = f2bf(a0.z); u0.w = f2bf(a0.w);
    u1.x = f2bf(a1.x); u1.y = f2bf(a1.y); u1.z = f2bf(a1.z); u1.w = f2bf(a1.w);
    ushort4* hr = (ushort4*)(hb + (size_t)n * 512);
    hr[lane] = u0;
    hr[64 + lane] = u1;
}

// ---- z = h @ Wb^T  (A [N,512] bf16; B [512,512] bf16 row-major-K) ----
#define LDSS 88   // bf16 elems per row: 176 B, 16B-aligned, 12-bank rotation
__global__ __launch_bounds__(256) void gemm_bt(const unsigned short* __restrict__ hb,
                                               const unsigned short* __restrict__ Wb,
                                               float* __restrict__ z, int N) {
    __shared__ unsigned short As[128 * LDSS];
    __shared__ unsigned short Bs[128 * LDSS];
    int tid = threadIdx.x;
    int wave = tid >> 6, lane = tid & 63;
    int quad = lane >> 4, l16 = lane & 15;
    int row0 = blockIdx.x * 128;
    int col0 = blockIdx.y * 128;
    int wr = (wave >> 1) * 64, wc = (wave & 1) * 64;

    floatx4 acc[4][4] = {};

    for (int k0 = 0; k0 < 512; k0 += 64) {
        // stage A: 128 rows x 64 k of bf16 (16B chunks)
        {
            int c8 = tid & 7;        // 8-bf16 chunk along k
            int rbase = tid >> 3;    // 0..31
#pragma unroll
            for (int p = 0; p < 4; ++p) {
                int r = p * 32 + rbase;
                int gr = row0 + r; if (gr >= N) gr = N - 1;
                float4 v = *(const float4*)(hb + (size_t)gr * 512 + k0 + c8 * 8);
                *(float4*)(As + r * LDSS + c8 * 8) = v;
            }
        }
        // stage B: 128 cols x 64 k, bf16 (16B chunks)
        {
            int c8 = tid & 7;
            int rbase = tid >> 3;    // 0..31
#pragma unroll
            for (int p = 0; p < 4; ++p) {
                int r = p * 32 + rbase;
                float4 v = *(const float4*)(Wb + (size_t)(col0 + r) * 512 + k0 + c8 * 8);
                *(float4*)(Bs + r * LDSS + c8 * 8) = v;
            }
        }
        __syncthreads();
#pragma unroll
        for (int kk = 0; kk < 2; ++kk) {
            short8 af[4], bfr[4];
#pragma unroll
            for (int i = 0; i < 4; ++i) {
                af[i]  = *(const short8*)(As + (wr + i * 16 + l16) * LDSS + kk * 32 + quad * 8);
                bfr[i] = *(const short8*)(Bs + (wc + i * 16 + l16) * LDSS + kk * 32 + quad * 8);
            }
#pragma unroll
            for (int i = 0; i < 4; ++i)
#pragma unroll
                for (int j = 0; j < 4; ++j)
                    acc[i][j] = __builtin_amdgcn_mfma_f32_16x16x32_bf16(af[i], bfr[j], acc[i][j], 0, 0, 0);
        }
        __syncthreads();
    }
    // epilogue: C/D layout col=lane&15, row=quad*4+reg
#pragma unroll
    for (int i = 0; i < 4; ++i) {
        int rl = wr + i * 16 + quad * 4;
#pragma unroll
        for (int j = 0; j < 4; ++j) {
            int col = col0 + wc + j * 16 + l16;
#pragma unroll
            for (int r = 0; r < 4; ++r) {
                int grow = row0 + rl + r;
                if (grow < N) z[(size_t)grow * 512 + col] = acc[i][j][r];
            }
        }
    }
}

// ---- per-column sum & sumsq over N rows ----
__global__ __launch_bounds__(512) void col_stats(const float* __restrict__ z,
                                                 float* __restrict__ s1,
                                                 float* __restrict__ s2, int N) {
    int col = threadIdx.x;
    float a = 0.f, b = 0.f;
    for (int r = blockIdx.x; r < N; r += gridDim.x) {
        float v = z[(size_t)r * 512 + col];
        a += v;
        b += v * v;
    }
    unsafeAtomicAdd(&s1[col], a);
    unsafeAtomicAdd(&s2[col], b);
}

__global__ void finalize(const float* __restrict__ s1, const float* __restrict__ s2,
                         const float* __restrict__ gamma, const float* __restrict__ beta,
                         float* __restrict__ scale, float* __restrict__ shift, int N) {
    int c = threadIdx.x;  // 512
    float inv = 1.f / (float)N;
    float mean = s1[c] * inv;
    float var = s2[c] * inv - mean * mean;
    if (var < 0.f) var = 0.f;
    float sc = gamma[c] * rsqrtf(var + 1e-5f);
    scale[c] = sc;
    shift[c] = beta[c] - mean * sc;
}

// ---- out = z * scale[col] + shift[col], in place on d_out ----
__global__ __launch_bounds__(256) void bn_apply(float4* __restrict__ z,
                                                const float4* __restrict__ scale,
                                                const float4* __restrict__ shift, int n4) {
    int i = blockIdx.x * 256 + threadIdx.x;
    if (i >= n4) return;
    int c4 = i & 127;   // 512/4 float4 per row
    float4 v = z[i], sc = scale[c4], sh = shift[c4];
    v.x = v.x * sc.x + sh.x;
    v.y = v.y * sc.y + sh.y;
    v.z = v.z * sc.z + sh.z;
    v.w = v.w * sc.w + sh.w;
    z[i] = v;
}

extern "C" void kernel_launch(void* const* d_in, const int* in_sizes, int n_in,
                              void* d_out, int out_size, void* d_ws, size_t ws_size,
                              hipStream_t stream) {
    const float* x     = (const float*)d_in[0];
    const int*   ei    = (const int*)d_in[1];
    const float* W     = (const float*)d_in[3];
    const float* gamma = (const float*)d_in[5];
    const float* beta  = (const float*)d_in[6];
    float* out = (float*)d_out;

    int N = in_sizes[0] / 512;   // 50000
    int E = in_sizes[1] / 2;     // 160000

    char* ws = (char*)d_ws;
    size_t off = 0;
    unsigned short* hb = (unsigned short*)(ws + off); off += (size_t)N * 512 * 2;
    unsigned short* Wb = (unsigned short*)(ws + off); off += 512 * 512 * 2;
    float* s1    = (float*)(ws + off); off += 2048;
    float* s2    = (float*)(ws + off); off += 2048;
    float* scale = (float*)(ws + off); off += 2048;
    float* shift = (float*)(ws + off); off += 2048;
    int*   flag  = (int*)(ws + off);   off += 256;
    int*   deg    = (int*)(ws + off);  off += (size_t)N * 4;
    int*   cursor = (int*)(ws + off);  off += (size_t)N * 4;
    int*   offs   = (int*)(ws + off);  off += (size_t)(N + 1) * 4 + 252; off &= ~(size_t)255;
    int*   srcbuf = (int*)(ws + off);  off += (size_t)E * 4;

    int n4 = N * 128;  // float4 count of [N,512]

    hipLaunchKernelGGL(detect_dtype, dim3(1), dim3(256), 0, stream, ei, flag);
    hipLaunchKernelGGL(conv_w, dim3(256), dim3(256), 0, stream, W, Wb, s1);
    hipLaunchKernelGGL(init_zero, dim3((2 * N + 255) / 256), dim3(256), 0, stream, deg, 2 * N);
    hipLaunchKernelGGL(deg_count, dim3((E + 255) / 256), dim3(256), 0, stream, ei, flag, deg, E, N);
    hipLaunchKernelGGL(scan_deg, dim3(1), dim3(1024), 0, stream, deg, offs, N);
    hipLaunchKernelGGL(bucket_fill, dim3((E + 255) / 256), dim3(256), 0, stream,
                       ei, flag, offs, cursor, srcbuf, E, N);
    hipLaunchKernelGGL(aggregate, dim3((N + 3) / 4), dim3(256), 0, stream,
                       x, offs, srcbuf, hb, N);
    hipLaunchKernelGGL(gemm_bt, dim3((N + 127) / 128, 4), dim3(256), 0, stream, hb, Wb, out, N);
    hipLaunchKernelGGL(col_stats, dim3(256), dim3(512), 0, stream, out, s1, s2, N);
    hipLaunchKernelGGL(finalize, dim3(1), dim3(512), 0, stream, s1, s2, gamma, beta, scale, shift, N);
    hipLaunchKernelGGL(bn_apply, dim3((n4 + 255) / 256), dim3(256), 0, stream,
                       (float4*)out, (const float4*)scale, (const float4*)shift, n4);
}

// Round 3
// 413.423 us; speedup vs baseline: 3.4781x; 1.0941x over previous
//
#include <hip/hip_runtime.h>
#include <hip/hip_bf16.h>

// GIN encoder: out = BN_train( (x + scatter_sum(x[src]->dst)) @ W^T + b ), b cancels in BN.
// N=50000, F=H=512, E=160000.
// R3: stats fused into gemm epilogue (col_stats removed); aggregate = 1 wave per half-row
//     with next-index prefetch.
// ws: hb[N*512 bf16] | Wb[512*512 bf16] | s1|s2|scale|shift[512 f32 each] | flag |
//     deg[N] | cursor[N] | offs[N+1] | srcbuf[E]   (~53 MB)

typedef __attribute__((ext_vector_type(8))) short short8;
typedef __attribute__((ext_vector_type(4))) float floatx4;

static __device__ __forceinline__ unsigned short f2bf(float f) {
    unsigned int u = __float_as_uint(f);
    u += 0x7FFFu + ((u >> 16) & 1u);   // round-to-nearest-even
    return (unsigned short)(u >> 16);
}

// ---- detect whether edge_index is int64 (odd int32 words all zero) or int32 ----
__global__ void detect_dtype(const int* __restrict__ ei, int* __restrict__ flag) {
    __shared__ int any_nz;
    if (threadIdx.x == 0) any_nz = 0;
    __syncthreads();
    if (ei[2 * threadIdx.x + 1] != 0) atomicOr(&any_nz, 1);
    __syncthreads();
    if (threadIdx.x == 0) *flag = (any_nz == 0) ? 1 : 0;  // 1 => int64 layout
}

static __device__ __forceinline__ void load_edge(const int* ei, int flag, int E, int e,
                                                 int& s, int& d) {
    if (flag) {
        const long long* e64 = (const long long*)ei;
        s = (int)e64[e];
        d = (int)e64[E + e];
    } else {
        s = ei[e];
        d = ei[E + e];
    }
}

// ---- W fp32 -> bf16, and zero the stats accumulators ----
__global__ __launch_bounds__(256) void conv_w(const float* __restrict__ W,
                                              unsigned short* __restrict__ Wb,
                                              float* __restrict__ stats /*1024 floats*/) {
    int i = blockIdx.x * 256 + threadIdx.x;   // 65536 threads x 4 elems = 512*512
    float4 v = ((const float4*)W)[i];
    ushort4 u;
    u.x = f2bf(v.x); u.y = f2bf(v.y); u.z = f2bf(v.z); u.w = f2bf(v.w);
    ((ushort4*)Wb)[i] = u;
    if (blockIdx.x == 0) {
        stats[threadIdx.x] = 0.f;
        stats[256 + threadIdx.x] = 0.f;
        stats[512 + threadIdx.x] = 0.f;
        stats[768 + threadIdx.x] = 0.f;
    }
}

// ---- zero deg + cursor (2N ints) ----
__global__ __launch_bounds__(256) void init_zero(int* __restrict__ p, int n) {
    int i = blockIdx.x * 256 + threadIdx.x;
    if (i < n) p[i] = 0;
}

// ---- per-dst degree count ----
__global__ __launch_bounds__(256) void deg_count(const int* __restrict__ ei,
                                                 const int* __restrict__ flag,
                                                 int* __restrict__ deg, int E, int N) {
    int e = blockIdx.x * 256 + threadIdx.x;
    if (e >= E) return;
    int s, d;
    load_edge(ei, *flag, E, e, s, d);
    if ((unsigned)d < (unsigned)N) atomicAdd(&deg[d], 1);
}

// ---- single-block exclusive scan of deg[N] -> offs[N+1] ----
__global__ __launch_bounds__(1024) void scan_deg(const int* __restrict__ deg,
                                                 int* __restrict__ offs, int N) {
    __shared__ int sums[1024];
    int t = threadIdx.x;
    int per = (N + 1023) / 1024;
    int beg = t * per, end = beg + per; if (end > N) end = N; if (beg > N) beg = N;
    int s = 0;
    for (int i = beg; i < end; ++i) s += deg[i];
    sums[t] = s;
    __syncthreads();
    for (int d = 1; d < 1024; d <<= 1) {
        int v = (t >= d) ? sums[t - d] : 0;
        __syncthreads();
        sums[t] += v;
        __syncthreads();
    }
    int run = (t > 0) ? sums[t - 1] : 0;
    for (int i = beg; i < end; ++i) { offs[i] = run; run += deg[i]; }
    if (t == 0) offs[N] = sums[1023];
}

// ---- scatter src indices into dst buckets ----
__global__ __launch_bounds__(256) void bucket_fill(const int* __restrict__ ei,
                                                   const int* __restrict__ flag,
                                                   const int* __restrict__ offs,
                                                   int* __restrict__ cursor,
                                                   int* __restrict__ srcbuf, int E, int N) {
    int e = blockIdx.x * 256 + threadIdx.x;
    if (e >= E) return;
    int s, d;
    load_edge(ei, *flag, E, e, s, d);
    if ((unsigned)d >= (unsigned)N || (unsigned)s >= (unsigned)N) return;
    int pos = offs[d] + atomicAdd(&cursor[d], 1);
    srcbuf[pos] = s;
}

// ---- h[n] = bf16( x[n] + sum_{s in bucket(n)} x[s] ); one wave per HALF row ----
__global__ __launch_bounds__(256) void aggregate(const float* __restrict__ x,
                                                 const int* __restrict__ offs,
                                                 const int* __restrict__ srcbuf,
                                                 unsigned short* __restrict__ hb, int N) {
    int w = blockIdx.x * 4 + (threadIdx.x >> 6);
    int n = w >> 1;
    if (n >= N) return;
    int half = (w & 1) * 64;
    int lane = (threadIdx.x & 63) + half;
    float4 a = ((const float4*)(x + (size_t)n * 512))[lane];
    int beg = offs[n], end = offs[n + 1];
    int j = beg;
    int sn = (j < end) ? srcbuf[j] : 0;
    while (j < end) {
        int s = sn;
        ++j;
        if (j < end) sn = srcbuf[j];   // prefetch next index past this row load
        float4 v = ((const float4*)(x + (size_t)s * 512))[lane];
        a.x += v.x; a.y += v.y; a.z += v.z; a.w += v.w;
    }
    ushort4 u;
    u.x = f2bf(a.x); u.y = f2bf(a.y); u.z = f2bf(a.z); u.w = f2bf(a.w);
    ((ushort4*)(hb + (size_t)n * 512))[lane] = u;
}

// ---- z = h @ Wb^T, with per-column sum/sumsq fused into the epilogue ----
#define LDSS 88   // bf16 elems per row: 176 B, 16B-aligned, 12-bank rotation
__global__ __launch_bounds__(256) void gemm_bt(const unsigned short* __restrict__ hb,
                                               const unsigned short* __restrict__ Wb,
                                               float* __restrict__ z,
                                               float* __restrict__ s1,
                                               float* __restrict__ s2, int N) {
    __shared__ unsigned short As[128 * LDSS];
    __shared__ unsigned short Bs[128 * LDSS];
    int tid = threadIdx.x;
    int wave = tid >> 6, lane = tid & 63;
    int quad = lane >> 4, l16 = lane & 15;
    int row0 = blockIdx.x * 128;
    int col0 = blockIdx.y * 128;
    int wr = (wave >> 1) * 64, wc = (wave & 1) * 64;

    floatx4 acc[4][4] = {};

    for (int k0 = 0; k0 < 512; k0 += 64) {
        // stage A: 128 rows x 64 k of bf16 (16B chunks)
        {
            int c8 = tid & 7;        // 8-bf16 chunk along k
            int rbase = tid >> 3;    // 0..31
#pragma unroll
            for (int p = 0; p < 4; ++p) {
                int r = p * 32 + rbase;
                int gr = row0 + r; if (gr >= N) gr = N - 1;
                float4 v = *(const float4*)(hb + (size_t)gr * 512 + k0 + c8 * 8);
                *(float4*)(As + r * LDSS + c8 * 8) = v;
            }
        }
        // stage B: 128 cols x 64 k, bf16 (16B chunks)
        {
            int c8 = tid & 7;
            int rbase = tid >> 3;    // 0..31
#pragma unroll
            for (int p = 0; p < 4; ++p) {
                int r = p * 32 + rbase;
                float4 v = *(const float4*)(Wb + (size_t)(col0 + r) * 512 + k0 + c8 * 8);
                *(float4*)(Bs + r * LDSS + c8 * 8) = v;
            }
        }
        __syncthreads();
#pragma unroll
        for (int kk = 0; kk < 2; ++kk) {
            short8 af[4], bfr[4];
#pragma unroll
            for (int i = 0; i < 4; ++i) {
                af[i]  = *(const short8*)(As + (wr + i * 16 + l16) * LDSS + kk * 32 + quad * 8);
                bfr[i] = *(const short8*)(Bs + (wc + i * 16 + l16) * LDSS + kk * 32 + quad * 8);
            }
#pragma unroll
            for (int i = 0; i < 4; ++i)
#pragma unroll
                for (int j = 0; j < 4; ++j)
                    acc[i][j] = __builtin_amdgcn_mfma_f32_16x16x32_bf16(af[i], bfr[j], acc[i][j], 0, 0, 0);
        }
        __syncthreads();
    }

    // epilogue: C/D layout col=lane&15, row=quad*4+reg; accumulate stats per column
    float p1[4] = {0.f, 0.f, 0.f, 0.f}, p2[4] = {0.f, 0.f, 0.f, 0.f};
#pragma unroll
    for (int i = 0; i < 4; ++i) {
        int rl = wr + i * 16 + quad * 4;
#pragma unroll
        for (int j = 0; j < 4; ++j) {
            int col = col0 + wc + j * 16 + l16;
#pragma unroll
            for (int r = 0; r < 4; ++r) {
                int grow = row0 + rl + r;
                if (grow < N) {
                    float v = acc[i][j][r];
                    z[(size_t)grow * 512 + col] = v;
                    p1[j] += v;
                    p2[j] += v * v;
                }
            }
        }
    }
    // reduce across the 4 quads (lanes 16/32 apart hold other row groups, same cols)
#pragma unroll
    for (int j = 0; j < 4; ++j) {
        p1[j] += __shfl_xor(p1[j], 16); p1[j] += __shfl_xor(p1[j], 32);
        p2[j] += __shfl_xor(p2[j], 16); p2[j] += __shfl_xor(p2[j], 32);
    }
    float* f1 = (float*)As;       // reuse LDS: 128 + 128 floats
    float* f2 = f1 + 128;
    if (tid < 256) f1[tid] = 0.f; // zeroes both f1 and f2
    __syncthreads();
    if (quad == 0) {
#pragma unroll
        for (int j = 0; j < 4; ++j) {
            atomicAdd(&f1[wc + j * 16 + l16], p1[j]);
            atomicAdd(&f2[wc + j * 16 + l16], p2[j]);
        }
    }
    __syncthreads();
    if (tid < 128) {
        unsafeAtomicAdd(&s1[col0 + tid], f1[tid]);
        unsafeAtomicAdd(&s2[col0 + tid], f2[tid]);
    }
}

__global__ void finalize(const float* __restrict__ s1, const float* __restrict__ s2,
                         const float* __restrict__ gamma, const float* __restrict__ beta,
                         float* __restrict__ scale, float* __restrict__ shift, int N) {
    int c = threadIdx.x;  // 512
    float inv = 1.f / (float)N;
    float mean = s1[c] * inv;
    float var = s2[c] * inv - mean * mean;
    if (var < 0.f) var = 0.f;
    float sc = gamma[c] * rsqrtf(var + 1e-5f);
    scale[c] = sc;
    shift[c] = beta[c] - mean * sc;
}

// ---- out = z * scale[col] + shift[col], in place on d_out ----
__global__ __launch_bounds__(256) void bn_apply(float4* __restrict__ z,
                                                const float4* __restrict__ scale,
                                                const float4* __restrict__ shift, int n4) {
    int i = blockIdx.x * 256 + threadIdx.x;
    if (i >= n4) return;
    int c4 = i & 127;   // 512/4 float4 per row
    float4 v = z[i], sc = scale[c4], sh = shift[c4];
    v.x = v.x * sc.x + sh.x;
    v.y = v.y * sc.y + sh.y;
    v.z = v.z * sc.z + sh.z;
    v.w = v.w * sc.w + sh.w;
    z[i] = v;
}

extern "C" void kernel_launch(void* const* d_in, const int* in_sizes, int n_in,
                              void* d_out, int out_size, void* d_ws, size_t ws_size,
                              hipStream_t stream) {
    const float* x     = (const float*)d_in[0];
    const int*   ei    = (const int*)d_in[1];
    const float* W     = (const float*)d_in[3];
    const float* gamma = (const float*)d_in[5];
    const float* beta  = (const float*)d_in[6];
    float* out = (float*)d_out;

    int N = in_sizes[0] / 512;   // 50000
    int E = in_sizes[1] / 2;     // 160000

    char* ws = (char*)d_ws;
    size_t off = 0;
    unsigned short* hb = (unsigned short*)(ws + off); off += (size_t)N * 512 * 2;
    unsigned short* Wb = (unsigned short*)(ws + off); off += 512 * 512 * 2;
    float* s1    = (float*)(ws + off); off += 2048;
    float* s2    = (float*)(ws + off); off += 2048;
    float* scale = (float*)(ws + off); off += 2048;
    float* shift = (float*)(ws + off); off += 2048;
    int*   flag  = (int*)(ws + off);   off += 256;
    int*   deg    = (int*)(ws + off);  off += (size_t)N * 4;
    int*   cursor = (int*)(ws + off);  off += (size_t)N * 4;
    int*   offs   = (int*)(ws + off);  off += (size_t)(N + 1) * 4 + 252; off &= ~(size_t)255;
    int*   srcbuf = (int*)(ws + off);  off += (size_t)E * 4;

    int n4 = N * 128;  // float4 count of [N,512]

    hipLaunchKernelGGL(detect_dtype, dim3(1), dim3(256), 0, stream, ei, flag);
    hipLaunchKernelGGL(conv_w, dim3(256), dim3(256), 0, stream, W, Wb, s1);
    hipLaunchKernelGGL(init_zero, dim3((2 * N + 255) / 256), dim3(256), 0, stream, deg, 2 * N);
    hipLaunchKernelGGL(deg_count, dim3((E + 255) / 256), dim3(256), 0, stream, ei, flag, deg, E, N);
    hipLaunchKernelGGL(scan_deg, dim3(1), dim3(1024), 0, stream, deg, offs, N);
    hipLaunchKernelGGL(bucket_fill, dim3((E + 255) / 256), dim3(256), 0, stream,
                       ei, flag, offs, cursor, srcbuf, E, N);
    hipLaunchKernelGGL(aggregate, dim3((2 * N + 3) / 4), dim3(256), 0, stream,
                       x, offs, srcbuf, hb, N);
    hipLaunchKernelGGL(gemm_bt, dim3((N + 127) / 128, 4), dim3(256), 0, stream,
                       hb, Wb, out, s1, s2, N);
    hipLaunchKernelGGL(finalize, dim3(1), dim3(512), 0, stream, s1, s2, gamma, beta, scale, shift, N);
    hipLaunchKernelGGL(bn_apply, dim3((n4 + 255) / 256), dim3(256), 0, stream,
                       (float4*)out, (const float4*)scale, (const float4*)shift, n4);
}

// Round 4
// 408.654 us; speedup vs baseline: 3.5186x; 1.0117x over previous
//
#include <hip/hip_runtime.h>
#include <hip/hip_bf16.h>

// GIN encoder: out = BN_train( (x + scatter_sum(x[src]->dst)) @ W^T + b ), b cancels in BN.
// N=50000, F=H=512, E=160000.
// R4: gemm staged via global_load_lds(16B) + XOR swizzle, z stored bf16;
//     aggregate unrolled x2 (two loads in flight); bn_apply reads bf16 z.
// ws: hb[N*512 bf16] | Wb[512*512 bf16] | s1|s2|scale|shift | flag |
//     union{ prep: deg[N] cursor[N] offs[N+1] srcbuf[E]  |  zb[N*512 bf16] }  (~103 MB)

typedef __attribute__((ext_vector_type(8))) short short8;
typedef __attribute__((ext_vector_type(4))) float floatx4;

static __device__ __forceinline__ unsigned short f2bf(float f) {
    unsigned int u = __float_as_uint(f);
    u += 0x7FFFu + ((u >> 16) & 1u);   // round-to-nearest-even
    return (unsigned short)(u >> 16);
}

static __device__ __forceinline__ void gload16(const void* g, void* l) {
    __builtin_amdgcn_global_load_lds(
        (const __attribute__((address_space(1))) unsigned int*)g,
        (__attribute__((address_space(3))) unsigned int*)l, 16, 0, 0);
}

// ---- detect whether edge_index is int64 (odd int32 words all zero) or int32 ----
__global__ void detect_dtype(const int* __restrict__ ei, int* __restrict__ flag) {
    __shared__ int any_nz;
    if (threadIdx.x == 0) any_nz = 0;
    __syncthreads();
    if (ei[2 * threadIdx.x + 1] != 0) atomicOr(&any_nz, 1);
    __syncthreads();
    if (threadIdx.x == 0) *flag = (any_nz == 0) ? 1 : 0;  // 1 => int64 layout
}

static __device__ __forceinline__ void load_edge(const int* ei, int flag, int E, int e,
                                                 int& s, int& d) {
    if (flag) {
        const long long* e64 = (const long long*)ei;
        s = (int)e64[e];
        d = (int)e64[E + e];
    } else {
        s = ei[e];
        d = ei[E + e];
    }
}

// ---- W fp32 -> bf16, zero stats + deg/cursor ----
__global__ __launch_bounds__(256) void conv_w(const float* __restrict__ W,
                                              unsigned short* __restrict__ Wb,
                                              float* __restrict__ stats /*1024 floats*/,
                                              int* __restrict__ dz, int ndz) {
    int i = blockIdx.x * 256 + threadIdx.x;   // 65536 threads x 4 elems = 512*512
    float4 v = ((const float4*)W)[i];
    ushort4 u;
    u.x = f2bf(v.x); u.y = f2bf(v.y); u.z = f2bf(v.z); u.w = f2bf(v.w);
    ((ushort4*)Wb)[i] = u;
    if (blockIdx.x == 0) {
        stats[threadIdx.x] = 0.f;
        stats[256 + threadIdx.x] = 0.f;
        stats[512 + threadIdx.x] = 0.f;
        stats[768 + threadIdx.x] = 0.f;
    }
    for (int k = i; k < ndz; k += 65536) dz[k] = 0;
}

// ---- per-dst degree count ----
__global__ __launch_bounds__(256) void deg_count(const int* __restrict__ ei,
                                                 const int* __restrict__ flag,
                                                 int* __restrict__ deg, int E, int N) {
    int e = blockIdx.x * 256 + threadIdx.x;
    if (e >= E) return;
    int s, d;
    load_edge(ei, *flag, E, e, s, d);
    if ((unsigned)d < (unsigned)N) atomicAdd(&deg[d], 1);
}

// ---- single-block exclusive scan of deg[N] -> offs[N+1] ----
__global__ __launch_bounds__(1024) void scan_deg(const int* __restrict__ deg,
                                                 int* __restrict__ offs, int N) {
    __shared__ int sums[1024];
    int t = threadIdx.x;
    int per = (N + 1023) / 1024;
    int beg = t * per, end = beg + per; if (end > N) end = N; if (beg > N) beg = N;
    int s = 0;
    for (int i = beg; i < end; ++i) s += deg[i];
    sums[t] = s;
    __syncthreads();
    for (int d = 1; d < 1024; d <<= 1) {
        int v = (t >= d) ? sums[t - d] : 0;
        __syncthreads();
        sums[t] += v;
        __syncthreads();
    }
    int run = (t > 0) ? sums[t - 1] : 0;
    for (int i = beg; i < end; ++i) { offs[i] = run; run += deg[i]; }
    if (t == 0) offs[N] = sums[1023];
}

// ---- scatter src indices into dst buckets ----
__global__ __launch_bounds__(256) void bucket_fill(const int* __restrict__ ei,
                                                   const int* __restrict__ flag,
                                                   const int* __restrict__ offs,
                                                   int* __restrict__ cursor,
                                                   int* __restrict__ srcbuf, int E, int N) {
    int e = blockIdx.x * 256 + threadIdx.x;
    if (e >= E) return;
    int s, d;
    load_edge(ei, *flag, E, e, s, d);
    if ((unsigned)d >= (unsigned)N || (unsigned)s >= (unsigned)N) return;
    int pos = offs[d] + atomicAdd(&cursor[d], 1);
    srcbuf[pos] = s;
}

// ---- h[n] = bf16( x[n] + sum_{s in bucket(n)} x[s] ); one wave per HALF row,
//      unrolled x2 so two gather loads are in flight ----
__global__ __launch_bounds__(256) void aggregate(const float* __restrict__ x,
                                                 const int* __restrict__ offs,
                                                 const int* __restrict__ srcbuf,
                                                 unsigned short* __restrict__ hb, int N) {
    int w = blockIdx.x * 4 + (threadIdx.x >> 6);
    int n = w >> 1;
    if (n >= N) return;
    int lane = (threadIdx.x & 63) + (w & 1) * 64;
    float4 a = ((const float4*)(x + (size_t)n * 512))[lane];
    float4 b = {0.f, 0.f, 0.f, 0.f};
    int beg = offs[n], end = offs[n + 1];
    int j = beg;
    for (; j + 2 <= end; j += 2) {
        int s0 = srcbuf[j], s1 = srcbuf[j + 1];
        float4 v0 = ((const float4*)(x + (size_t)s0 * 512))[lane];
        float4 v1 = ((const float4*)(x + (size_t)s1 * 512))[lane];
        a.x += v0.x; a.y += v0.y; a.z += v0.z; a.w += v0.w;
        b.x += v1.x; b.y += v1.y; b.z += v1.z; b.w += v1.w;
    }
    if (j < end) {
        int s0 = srcbuf[j];
        float4 v0 = ((const float4*)(x + (size_t)s0 * 512))[lane];
        a.x += v0.x; a.y += v0.y; a.z += v0.z; a.w += v0.w;
    }
    a.x += b.x; a.y += b.y; a.z += b.z; a.w += b.w;
    ushort4 u;
    u.x = f2bf(a.x); u.y = f2bf(a.y); u.z = f2bf(a.z); u.w = f2bf(a.w);
    ((ushort4*)(hb + (size_t)n * 512))[lane] = u;
}

// ---- z = h @ Wb^T (bf16 out), stats fused. global_load_lds + XOR-swizzled LDS ----
__global__ __launch_bounds__(256) void gemm_bt(const unsigned short* __restrict__ hb,
                                               const unsigned short* __restrict__ Wb,
                                               unsigned short* __restrict__ zb,
                                               float* __restrict__ s1,
                                               float* __restrict__ s2, int N) {
    __shared__ unsigned short As[128 * 64];   // row-major, 64 bf16 (128 B) per row
    __shared__ unsigned short Bs[128 * 64];
    int tid = threadIdx.x;
    int wave = tid >> 6, lane = tid & 63;
    int quad = lane >> 4, l16 = lane & 15;
    int r8 = lane >> 3;          // 0..7: row within this wave's 8-row strip
    int c8 = lane & 7;           // 0..7: 16B chunk within 128B row
    int swz = c8 ^ r8;           // XOR swizzle (applied on global side)
    int row0 = blockIdx.x * 128;
    int col0 = blockIdx.y * 128;
    int wr = (wave >> 1) * 64, wc = (wave & 1) * 64;

    floatx4 acc[4][4] = {};

    for (int k0 = 0; k0 < 512; k0 += 64) {
#pragma unroll
        for (int p = 0; p < 4; ++p) {
            int strip = p * 4 + wave;            // 0..15
            int rt = strip * 8 + r8;             // tile row 0..127
            // A: rows may run past N by <48; lands in Wb region (finite bf16) — never used
            gload16(hb + (size_t)(row0 + rt) * 512 + k0 + swz * 8, As + strip * 512);
            gload16(Wb + (size_t)(col0 + rt) * 512 + k0 + swz * 8, Bs + strip * 512);
        }
        __syncthreads();
#pragma unroll
        for (int kk = 0; kk < 2; ++kk) {
            short8 af[4], bfr[4];
#pragma unroll
            for (int i = 0; i < 4; ++i) {
                int ch = (kk * 4 + quad) ^ (l16 & 7);
                af[i]  = *(const short8*)(As + (wr + i * 16 + l16) * 64 + ch * 8);
                bfr[i] = *(const short8*)(Bs + (wc + i * 16 + l16) * 64 + ch * 8);
            }
#pragma unroll
            for (int i = 0; i < 4; ++i)
#pragma unroll
                for (int j = 0; j < 4; ++j)
                    acc[i][j] = __builtin_amdgcn_mfma_f32_16x16x32_bf16(af[i], bfr[j], acc[i][j], 0, 0, 0);
        }
        __syncthreads();
    }

    // epilogue: C/D layout col=lane&15, row=quad*4+reg; z in bf16; stats per column
    float p1[4] = {0.f, 0.f, 0.f, 0.f}, p2[4] = {0.f, 0.f, 0.f, 0.f};
#pragma unroll
    for (int i = 0; i < 4; ++i) {
        int rl = wr + i * 16 + quad * 4;
#pragma unroll
        for (int j = 0; j < 4; ++j) {
            int col = col0 + wc + j * 16 + l16;
#pragma unroll
            for (int r = 0; r < 4; ++r) {
                int grow = row0 + rl + r;
                if (grow < N) {
                    float v = acc[i][j][r];
                    zb[(size_t)grow * 512 + col] = f2bf(v);
                    p1[j] += v;
                    p2[j] += v * v;
                }
            }
        }
    }
#pragma unroll
    for (int j = 0; j < 4; ++j) {
        p1[j] += __shfl_xor(p1[j], 16); p1[j] += __shfl_xor(p1[j], 32);
        p2[j] += __shfl_xor(p2[j], 16); p2[j] += __shfl_xor(p2[j], 32);
    }
    float* f1 = (float*)As;       // reuse LDS: 128 + 128 floats
    float* f2 = f1 + 128;
    if (tid < 256) f1[tid] = 0.f; // zeroes both f1 and f2
    __syncthreads();
    if (quad == 0) {
#pragma unroll
        for (int j = 0; j < 4; ++j) {
            atomicAdd(&f1[wc + j * 16 + l16], p1[j]);
            atomicAdd(&f2[wc + j * 16 + l16], p2[j]);
        }
    }
    __syncthreads();
    if (tid < 128) {
        unsafeAtomicAdd(&s1[col0 + tid], f1[tid]);
        unsafeAtomicAdd(&s2[col0 + tid], f2[tid]);
    }
}

__global__ void finalize(const float* __restrict__ s1, const float* __restrict__ s2,
                         const float* __restrict__ gamma, const float* __restrict__ beta,
                         float* __restrict__ scale, float* __restrict__ shift, int N) {
    int c = threadIdx.x;  // 512
    float inv = 1.f / (float)N;
    float mean = s1[c] * inv;
    float var = s2[c] * inv - mean * mean;
    if (var < 0.f) var = 0.f;
    float sc = gamma[c] * rsqrtf(var + 1e-5f);
    scale[c] = sc;
    shift[c] = beta[c] - mean * sc;
}

// ---- out = zb * scale[col] + shift[col]; zb bf16 -> out fp32 ----
__global__ __launch_bounds__(256) void bn_apply(const ushort4* __restrict__ zb,
                                                float4* __restrict__ out,
                                                const float4* __restrict__ scale,
                                                const float4* __restrict__ shift, int n4) {
    int i = blockIdx.x * 256 + threadIdx.x;
    if (i >= n4) return;
    int c4 = i & 127;   // 512/4 groups per row
    ushort4 u = zb[i];
    float4 sc = scale[c4], sh = shift[c4];
    float4 v;
    v.x = __uint_as_float((unsigned)u.x << 16) * sc.x + sh.x;
    v.y = __uint_as_float((unsigned)u.y << 16) * sc.y + sh.y;
    v.z = __uint_as_float((unsigned)u.z << 16) * sc.z + sh.z;
    v.w = __uint_as_float((unsigned)u.w << 16) * sc.w + sh.w;
    out[i] = v;
}

extern "C" void kernel_launch(void* const* d_in, const int* in_sizes, int n_in,
                              void* d_out, int out_size, void* d_ws, size_t ws_size,
                              hipStream_t stream) {
    const float* x     = (const float*)d_in[0];
    const int*   ei    = (const int*)d_in[1];
    const float* W     = (const float*)d_in[3];
    const float* gamma = (const float*)d_in[5];
    const float* beta  = (const float*)d_in[6];
    float* out = (float*)d_out;

    int N = in_sizes[0] / 512;   // 50000
    int E = in_sizes[1] / 2;     // 160000

    char* ws = (char*)d_ws;
    size_t off = 0;
    unsigned short* hb = (unsigned short*)(ws + off); off += (size_t)N * 512 * 2;
    unsigned short* Wb = (unsigned short*)(ws + off); off += 512 * 512 * 2;
    float* s1    = (float*)(ws + off); off += 2048;
    float* s2    = (float*)(ws + off); off += 2048;
    float* scale = (float*)(ws + off); off += 2048;
    float* shift = (float*)(ws + off); off += 2048;
    int*   flag  = (int*)(ws + off);   off += 256;
    // union region: prep buffers live until aggregate; zb written by gemm afterwards
    size_t ualias = off;
    int*   deg    = (int*)(ws + off);  off += (size_t)N * 4;
    int*   cursor = (int*)(ws + off);  off += (size_t)N * 4;
    int*   offs   = (int*)(ws + off);  off += (size_t)(N + 1) * 4 + 252; off &= ~(size_t)255;
    int*   srcbuf = (int*)(ws + off);
    unsigned short* zb = (unsigned short*)(ws + ualias);  // N*512*2 bytes, aliases prep

    int n4 = N * 128;  // float4 / ushort4 count of [N,512]

    hipLaunchKernelGGL(detect_dtype, dim3(1), dim3(256), 0, stream, ei, flag);
    hipLaunchKernelGGL(conv_w, dim3(256), dim3(256), 0, stream, W, Wb, s1, deg, 2 * N);
    hipLaunchKernelGGL(deg_count, dim3((E + 255) / 256), dim3(256), 0, stream, ei, flag, deg, E, N);
    hipLaunchKernelGGL(scan_deg, dim3(1), dim3(1024), 0, stream, deg, offs, N);
    hipLaunchKernelGGL(bucket_fill, dim3((E + 255) / 256), dim3(256), 0, stream,
                       ei, flag, offs, cursor, srcbuf, E, N);
    hipLaunchKernelGGL(aggregate, dim3((2 * N + 3) / 4), dim3(256), 0, stream,
                       x, offs, srcbuf, hb, N);
    hipLaunchKernelGGL(gemm_bt, dim3((N + 127) / 128, 4), dim3(256), 0, stream,
                       hb, Wb, zb, s1, s2, N);
    hipLaunchKernelGGL(finalize, dim3(1), dim3(512), 0, stream, s1, s2, gamma, beta, scale, shift, N);
    hipLaunchKernelGGL(bn_apply, dim3((n4 + 255) / 256), dim3(256), 0, stream,
                       (const ushort4*)zb, (float4*)out, (const float4*)scale, (const float4*)shift, n4);
}